// Round 1
// baseline (188.438 us; speedup 1.0000x reference)
//
#include <hip/hip_runtime.h>

#define NN 8192
#define INF_ 512
#define OUTF 256
#define LOG2E 1.4426950408889634f

typedef __attribute__((ext_vector_type(8))) short short8;
typedef __attribute__((ext_vector_type(4))) float f4;
typedef __attribute__((ext_vector_type(4))) int i4;

__device__ __forceinline__ unsigned short f2bf(float f) {
  union { float f; unsigned u; } v; v.f = f;
  unsigned r = v.u + 0x7fffu + ((v.u >> 16) & 1u);
  return (unsigned short)(r >> 16);
}
__device__ __forceinline__ float bf2f(unsigned short h) {
  union { unsigned u; float f; } v; v.u = ((unsigned)h) << 16;
  return v.f;
}

// ---------------- K0: W (512x256 f32) -> W^T hi/lo bf16 (256x512) ----------------
__global__ void k_wsplit(const float* __restrict__ W, unsigned short* __restrict__ Whi,
                         unsigned short* __restrict__ Wlo) {
  int idx = blockIdx.x * 256 + threadIdx.x;   // 131072
  int k = idx >> 8, c = idx & 255;
  float w = W[idx];
  unsigned short hi = f2bf(w);
  unsigned short lo = f2bf(w - bf2f(hi));
  Whi[c * INF_ + k] = hi;
  Wlo[c * INF_ + k] = lo;
}

// ---------------- K1: h = x@W (split-3 bf16 MFMA), h_T bf16, s1 = h@a1, s2 = h@a2 ----------------
// 1 wave per block; block b: rows [(b>>1)*16, +16), cols [(b&1)*128, +128)
__global__ void __launch_bounds__(64) k_h(
    const float* __restrict__ x, const float* __restrict__ a,
    const unsigned short* __restrict__ Whi, const unsigned short* __restrict__ Wlo,
    unsigned short* __restrict__ hT, float* __restrict__ s1, float* __restrict__ s2) {
  const int b = blockIdx.x;
  const int rowbase = (b >> 1) * 16;
  const int colbase = (b & 1) * 128;
  const int l = threadIdx.x;
  const int r15 = l & 15, kg = l >> 4;

  f4 acc[8];
#pragma unroll
  for (int i = 0; i < 8; ++i) acc[i] = (f4){0.f, 0.f, 0.f, 0.f};

  for (int kk = 0; kk < INF_; kk += 32) {
    const float* xp = x + (rowbase + r15) * INF_ + kk + kg * 8;
    f4 xa = *(const f4*)xp;
    f4 xb = *(const f4*)(xp + 4);
    short8 ahi, alo;
#pragma unroll
    for (int e = 0; e < 8; ++e) {
      float f = (e < 4) ? xa[e] : xb[e - 4];
      unsigned short h = f2bf(f);
      ahi[e] = (short)h;
      alo[e] = (short)f2bf(f - bf2f(h));
    }
#pragma unroll
    for (int cg = 0; cg < 8; ++cg) {
      int col = colbase + cg * 16 + r15;
      const short8 bhi = *(const short8*)(Whi + col * INF_ + kk + kg * 8);
      const short8 blo = *(const short8*)(Wlo + col * INF_ + kk + kg * 8);
      acc[cg] = __builtin_amdgcn_mfma_f32_16x16x32_bf16(ahi, bhi, acc[cg], 0, 0, 0);
      acc[cg] = __builtin_amdgcn_mfma_f32_16x16x32_bf16(ahi, blo, acc[cg], 0, 0, 0);
      acc[cg] = __builtin_amdgcn_mfma_f32_16x16x32_bf16(alo, bhi, acc[cg], 0, 0, 0);
    }
  }
  // epilogue: store h_T bf16, accumulate s1/s2 partials
  float sp1[4] = {0, 0, 0, 0}, sp2[4] = {0, 0, 0, 0};
#pragma unroll
  for (int cg = 0; cg < 8; ++cg) {
    int col = colbase + cg * 16 + r15;
    float a1v = a[col], a2v = a[OUTF + col];
#pragma unroll
    for (int r = 0; r < 4; ++r) {
      float v = acc[cg][r];
      int row = rowbase + kg * 4 + r;
      hT[col * NN + row] = f2bf(v);
      sp1[r] += v * a1v;
      sp2[r] += v * a2v;
    }
  }
#pragma unroll
  for (int r = 0; r < 4; ++r) {
#pragma unroll
    for (int m = 1; m < 16; m <<= 1) {
      sp1[r] += __shfl_xor(sp1[r], m, 16);
      sp2[r] += __shfl_xor(sp2[r], m, 16);
    }
    if (r15 == 0) {
      atomicAdd(&s1[rowbase + kg * 4 + r], sp1[r]);
      atomicAdd(&s2[rowbase + kg * 4 + r], sp2[r]);
    }
  }
}

// ---------------- K2: fused mask + exp + (attention-partial @ h) ----------------
// 512 blocks: chunk = b&7 (j range of 1024), rowblk = b>>3 (128 rows).
// 4 waves; wave wr owns rows [rowblk*128 + wr*32, +32) x all 256 cols.
__global__ void __launch_bounds__(256, 2) k_attn(
    const int* __restrict__ adj, const float* __restrict__ s1G,
    const float* __restrict__ s2G, const unsigned short* __restrict__ hT,
    float* __restrict__ accG, float* __restrict__ lG) {
  __shared__ unsigned short lds[2][8192];   // 2 x 16 KB B-tiles [256 c][32 j] swizzled
  const int b = blockIdx.x;
  const int chunk = b & 7;
  const int rowblk = b >> 3;
  const int tid = threadIdx.x;
  const int wr = tid >> 6;
  const int l = tid & 63;
  const int r15 = l & 15, kg = l >> 4;
  const int rowbase = rowblk * 128 + wr * 32;
  const int row0 = rowbase + r15;
  const int row1 = rowbase + 16 + r15;
  const int jbase = chunk * 1024;

  const float s1_0 = s1G[row0];
  const float s1_1 = s1G[row1];

  f4 acc[2][16];
#pragma unroll
  for (int g = 0; g < 2; ++g)
#pragma unroll
    for (int c = 0; c < 16; ++c) acc[g][c] = (f4){0.f, 0.f, 0.f, 0.f};
  float lsum0 = 0.f, lsum1 = 0.f;

  const int c_st = wr * 64 + (l >> 2);  // staging: c row (plus q*16), slot = l&3
  const int s_st = l & 3;

  // prologue: stage tile 0, prefetch adj/s2 regs for t=0
  {
#pragma unroll
    for (int q = 0; q < 4; ++q) {
      int c = c_st + q * 16;
      int kp = (s_st - (c >> 1)) & 3;                 // inverse swizzle on SOURCE
      const unsigned short* src = hT + c * NN + jbase + kp * 8;
      unsigned short* dst = &lds[0][(wr * 64 + q * 16) * 32];
      __builtin_amdgcn_global_load_lds(
          (const __attribute__((address_space(1))) unsigned int*)src,
          (__attribute__((address_space(3))) unsigned int*)dst, 16, 0, 0);
    }
  }
  i4 adjb[2][2][2];
  f4 s2b[2][2];
  {
    const int* ap0 = adj + row0 * NN + jbase + kg * 8;
    const int* ap1 = adj + row1 * NN + jbase + kg * 8;
    adjb[0][0][0] = *(const i4*)ap0; adjb[0][0][1] = *(const i4*)(ap0 + 4);
    adjb[0][1][0] = *(const i4*)ap1; adjb[0][1][1] = *(const i4*)(ap1 + 4);
    const float* sp = s2G + jbase + kg * 8;
    s2b[0][0] = *(const f4*)sp; s2b[0][1] = *(const f4*)(sp + 4);
  }
  __syncthreads();

#pragma unroll 2
  for (int t = 0; t < 32; ++t) {
    const int cur = t & 1, nxt = cur ^ 1;
    if (t + 1 < 32) {
      int j0 = jbase + (t + 1) * 32;
#pragma unroll
      for (int q = 0; q < 4; ++q) {
        int c = c_st + q * 16;
        int kp = (s_st - (c >> 1)) & 3;
        const unsigned short* src = hT + c * NN + j0 + kp * 8;
        unsigned short* dst = &lds[nxt][(wr * 64 + q * 16) * 32];
        __builtin_amdgcn_global_load_lds(
            (const __attribute__((address_space(1))) unsigned int*)src,
            (__attribute__((address_space(3))) unsigned int*)dst, 16, 0, 0);
      }
      const int* ap0 = adj + row0 * NN + j0 + kg * 8;
      const int* ap1 = adj + row1 * NN + j0 + kg * 8;
      adjb[nxt][0][0] = *(const i4*)ap0; adjb[nxt][0][1] = *(const i4*)(ap0 + 4);
      adjb[nxt][1][0] = *(const i4*)ap1; adjb[nxt][1][1] = *(const i4*)(ap1 + 4);
      const float* sp = s2G + j0 + kg * 8;
      s2b[nxt][0] = *(const f4*)sp; s2b[nxt][1] = *(const f4*)(sp + 4);
    }
    // A-fragments: w = adj ? exp(leakyrelu(s1+s2)) : 0   (no shift needed; see header)
    short8 af0, af1;
#pragma unroll
    for (int e = 0; e < 8; ++e) {
      float sv = (e < 4) ? s2b[cur][0][e] : s2b[cur][1][e - 4];
      int m0 = (e < 4) ? adjb[cur][0][0][e] : adjb[cur][0][1][e - 4];
      int m1 = (e < 4) ? adjb[cur][1][0][e] : adjb[cur][1][1][e - 4];
      float x0 = s1_0 + sv, x1 = s1_1 + sv;
      float lr0 = fmaxf(x0, 0.2f * x0);
      float lr1 = fmaxf(x1, 0.2f * x1);
      float p0 = __builtin_amdgcn_exp2f(lr0 * LOG2E);
      float p1 = __builtin_amdgcn_exp2f(lr1 * LOG2E);
      float w0 = (m0 > 0) ? p0 : 0.0f;
      float w1 = (m1 > 0) ? p1 : 0.0f;
      unsigned short h0 = f2bf(w0), h1 = f2bf(w1);
      af0[e] = (short)h0; af1[e] = (short)h1;
      lsum0 += bf2f(h0);  // sum the *rounded* weights -> exact convex combination
      lsum1 += bf2f(h1);
    }
    // B from LDS (swizzled), 16 col-groups, each frag feeds both row-groups
#pragma unroll
    for (int cg = 0; cg < 16; ++cg) {
      int c = cg * 16 + r15;
      int slot = (kg + (c >> 1)) & 3;
      const short8 bfrag = *(const short8*)&lds[cur][c * 32 + slot * 8];
      acc[0][cg] = __builtin_amdgcn_mfma_f32_16x16x32_bf16(af0, bfrag, acc[0][cg], 0, 0, 0);
      acc[1][cg] = __builtin_amdgcn_mfma_f32_16x16x32_bf16(af1, bfrag, acc[1][cg], 0, 0, 0);
    }
    __syncthreads();
  }

  // epilogue: reduce row-sums over the 4 k-groups, then atomics
  lsum0 += __shfl_xor(lsum0, 16, 64);
  lsum0 += __shfl_xor(lsum0, 32, 64);
  lsum1 += __shfl_xor(lsum1, 16, 64);
  lsum1 += __shfl_xor(lsum1, 32, 64);
  if (kg == 0) {
    atomicAdd(&lG[row0], lsum0);
    atomicAdd(&lG[row1], lsum1);
  }
#pragma unroll
  for (int g = 0; g < 2; ++g)
#pragma unroll
    for (int cg = 0; cg < 16; ++cg)
#pragma unroll
      for (int r = 0; r < 4; ++r) {
        int row = rowbase + g * 16 + kg * 4 + r;
        int col = cg * 16 + r15;
        atomicAdd(&accG[row * OUTF + col], acc[g][cg][r]);
      }
}

// ---------------- K3: out = acc / l + bias ----------------
__global__ void k_final(const float* __restrict__ accG, const float* __restrict__ lG,
                        const float* __restrict__ bias, float* __restrict__ out) {
  int idx = blockIdx.x * 256 + threadIdx.x;  // f4 index, 524288 total
  int row = idx >> 6;
  int c4 = idx & 63;
  f4 v = ((const f4*)accG)[idx];
  float inv = 1.0f / lG[row];
  f4 bb = ((const f4*)bias)[c4];
  f4 o;
#pragma unroll
  for (int e = 0; e < 4; ++e) o[e] = v[e] * inv + bb[e];
  ((f4*)out)[idx] = o;
}

extern "C" void kernel_launch(void* const* d_in, const int* in_sizes, int n_in,
                              void* d_out, int out_size, void* d_ws, size_t ws_size,
                              hipStream_t stream) {
  const float* x = (const float*)d_in[0];
  const int* adj = (const int*)d_in[1];
  const float* W = (const float*)d_in[2];
  const float* a = (const float*)d_in[3];
  const float* bias = (const float*)d_in[4];
  float* out = (float*)d_out;

  char* ws = (char*)d_ws;
  float* accG = (float*)(ws);                                // 8 MB
  float* lG   = (float*)(ws + 8388608);                      // 32 KB
  float* s1   = (float*)(ws + 8421376);                      // 32 KB
  float* s2   = (float*)(ws + 8454144);                      // 32 KB
  unsigned short* hT  = (unsigned short*)(ws + 8486912);     // 4 MB  [256][8192] bf16
  unsigned short* Whi = (unsigned short*)(ws + 12681216);    // 256 KB [256][512]
  unsigned short* Wlo = (unsigned short*)(ws + 12943360);    // 256 KB

  hipMemsetAsync(accG, 0, 8486912, stream);  // zero acc + l + s1 + s2
  k_wsplit<<<512, 256, 0, stream>>>(W, Whi, Wlo);
  k_h<<<1024, 64, 0, stream>>>(x, a, Whi, Wlo, hT, s1, s2);
  k_attn<<<512, 256, 0, stream>>>(adj, s1, s2, hT, accG, lG);
  k_final<<<2048, 256, 0, stream>>>(accG, lG, bias, out);
}